// Round 1
// baseline (511.145 us; speedup 1.0000x reference)
//
#include <hip/hip_runtime.h>

#define NRAYS 131072
#define NS 64      // coarse samples (z_vals per ray)
#define NI 128     // importance samples
#define NM 63      // bins (z_mid entries) == cdf length
#define NW 62      // interior weights used
#define NT 192     // merged samples per ray (NS + NI)

// One ray per wave64. All per-ray arrays (z_vals, z_mid, cdf, z_samples) are
// register-resident (one element per lane); all searches/gathers use __shfl
// (ds_bpermute: conflict-free, no LDS round-trip). Waves are fully
// independent -> no __syncthreads. LDS holds only the merged 192-array.
__global__ __launch_bounds__(256) void importance_kernel(
    const float* __restrict__ rays_o,
    const float* __restrict__ rays_d,
    const float* __restrict__ z_vals,
    const float* __restrict__ weights,
    float* __restrict__ out_pts,    // [N, 192, 3]
    float* __restrict__ out_zall,   // [N, 192]
    float* __restrict__ out_zs)     // [N, 128]
{
    __shared__ float s_zall[4][NT];   // 3 KB/block

    const int wave = threadIdx.x >> 6;
    const int lane = threadIdx.x & 63;
    const int ray  = (blockIdx.x << 2) + wave;   // NRAYS % 4 == 0

    const float* zv_g = z_vals  + (size_t)ray * NS;
    const float* w_g  = weights + (size_t)ray * NS;

    // ---- stage inputs into registers ----
    const float zvl = zv_g[lane];                      // z_vals[lane]
    float od = 0.0f;
    if (lane < 6)
        od = (lane < 3) ? rays_o[ray * 3 + lane] : rays_d[ray * 3 + lane - 3];
    const float wl = (lane < NW) ? (w_g[lane + 1] + 1e-5f) : 0.0f;

    const float o0 = __shfl(od, 0, 64), o1 = __shfl(od, 1, 64), o2 = __shfl(od, 2, 64);
    const float d0 = __shfl(od, 3, 64), d1 = __shfl(od, 4, 64), d2 = __shfl(od, 5, 64);

    // z_mid[l] in lane l (valid for l < 63)
    const float zm = 0.5f * (zvl + __shfl_down(zvl, 1, 64));

    // ---- inclusive scan of wl (Hillis-Steele over 64 lanes) ----
    float scan = wl;
    #pragma unroll
    for (int off = 1; off < 64; off <<= 1) {
        const float up = __shfl_up(scan, off, 64);
        if (lane >= off) scan += up;
    }
    const float total = __shfl(scan, NW - 1, 64);      // lane 61 holds full sum
    // cdf[l] in lane l: cdf[0] = 0, cdf[l] = scan[l-1]/total  (valid l <= 62)
    const float sp  = __shfl_up(scan, 1, 64);
    const float cdf = (lane == 0) ? 0.0f : sp / total;

    // ---- inverse-CDF sampling: 2 samples per lane (j = lane, lane+64) ----
    // Fixed-trip searches keep all 64 lanes active at every __shfl
    // (shfl from an inactive lane is undefined on CDNA).
    float xv[2]; int xb[2];
    #pragma unroll
    for (int rep = 0; rep < 2; rep++) {
        const int j = lane + (rep << 6);
        // np.linspace(0,1,128): round_f32(j/127 computed in f64)
        const float u = (float)((double)j * (1.0 / 127.0));
        // searchsorted(cdf, u, side='right') over cdf[0..62]; range 63 -> 6 iters
        int lo = 0, hi = NM;
        #pragma unroll
        for (int it = 0; it < 6; it++) {
            const int mid = (lo + hi) >> 1;            // <= 62 while lo<hi
            const float v = __shfl(cdf, mid, 64);
            if (lo < hi) { if (v <= u) lo = mid + 1; else hi = mid; }
        }
        int below = lo - 1; if (below < 0) below = 0;
        int above = lo;     if (above > NM - 1) above = NM - 1;
        const float cb = __shfl(cdf, below, 64);
        const float ca = __shfl(cdf, above, 64);
        const float bb = __shfl(zm,  below, 64);
        const float ba = __shfl(zm,  above, 64);
        float denom = ca - cb;
        if (denom < 1e-5f) denom = 1.0f;
        const float t = (u - cb) / denom;
        xv[rep] = bb + t * (ba - bb);
        xb[rep] = below;
    }
    const float zs0 = xv[0], zs1 = xv[1];

    // ---- merge: place this lane's z_vals element ----
    // pos = lane + count(zs < a)  (z_vals wins ties); range 128 -> 8 iters
    {
        int lo = 0, hi = NI;
        #pragma unroll
        for (int it = 0; it < 8; it++) {
            const int mid = (lo + hi) >> 1;
            const int m6  = mid & 63;
            const float v0 = __shfl(zs0, m6, 64);
            const float v1 = __shfl(zs1, m6, 64);
            const float v  = (mid < 64) ? v0 : v1;
            if (lo < hi) { if (v < zvl) lo = mid + 1; else hi = mid; }
        }
        s_zall[wave][lane + lo] = zvl;
    }

    // ---- merge: place the 2 samples ----
    // pos = j + count(zv <= x). Sample x from bin `below` satisfies
    // x >= z_mid[below] >= z_vals[below], so count >= below+1; ascend from
    // there (exact; ~1-2 advances expected since x < z_vals[below+2]).
    #pragma unroll
    for (int rep = 0; rep < 2; rep++) {
        const float x = xv[rep];
        int c = xb[rep] + 1;
        while (true) {
            const int  idx = (c < NS) ? c : (NS - 1);
            const float zc = __shfl(zvl, idx, 64);     // all lanes active
            const bool adv = (c < NS) && (zc <= x);
            if (!__any(adv)) break;
            if (adv) c++;
        }
        s_zall[wave][lane + (rep << 6) + c] = x;
    }

    // Wave-local ordering: drain the scatter ds_writes before re-reading.
    // (Waves never share LDS slices -> no block barrier needed.)
    asm volatile("s_waitcnt lgkmcnt(0)" ::: "memory");

    // ---- outputs (lane-contiguous coalesced dword stores) ----
    const float* zallp = s_zall[wave];
    const size_t pts_base = (size_t)ray * (NT * 3);
    #pragma unroll
    for (int rep = 0; rep < 9; rep++) {
        const int i = lane + (rep << 6);
        const int k = i / 3;            // magic-mul div
        const int d = i - 3 * k;
        const float z  = zallp[k];
        const float o  = (d == 0) ? o0 : ((d == 1) ? o1 : o2);
        const float dd = (d == 0) ? d0 : ((d == 1) ? d1 : d2);
        out_pts[pts_base + i] = o + dd * z;
    }
    const size_t za_base = (size_t)ray * NT;
    #pragma unroll
    for (int rep = 0; rep < 3; rep++) {
        const int i = lane + (rep << 6);
        out_zall[za_base + i] = zallp[i];
    }
    const size_t zs_base = (size_t)ray * NI;
    out_zs[zs_base + lane]      = zs0;
    out_zs[zs_base + 64 + lane] = zs1;
}

extern "C" void kernel_launch(void* const* d_in, const int* in_sizes, int n_in,
                              void* d_out, int out_size, void* d_ws, size_t ws_size,
                              hipStream_t stream) {
    const float* rays_o  = (const float*)d_in[0];
    const float* rays_d  = (const float*)d_in[1];
    const float* z_vals  = (const float*)d_in[2];
    const float* weights = (const float*)d_in[3];

    float* out      = (float*)d_out;
    float* out_pts  = out;                                  // N*192*3
    float* out_zall = out + (size_t)NRAYS * NT * 3;         // N*192
    float* out_zs   = out_zall + (size_t)NRAYS * NT;        // N*128

    dim3 grid(NRAYS / 4), block(256);
    hipLaunchKernelGGL(importance_kernel, grid, block, 0, stream,
                       rays_o, rays_d, z_vals, weights,
                       out_pts, out_zall, out_zs);
}